// Round 9
// baseline (440.388 us; speedup 1.0000x reference)
//
#include <hip/hip_runtime.h>
#include <hip/hip_bf16.h>
#include <stdint.h>

// ---- problem constants (fixed shapes) ----
#define BTOT   256      // B*T frames
#define LX     197      // tokens incl CLS
#define CDIM   768
#define CADIM  384
#define TFR    8
#define LM1    196      // L-1
#define MTOT   50176    // BTOT*LM1

typedef unsigned short u16;
typedef short          bf16x8 __attribute__((ext_vector_type(8)));
typedef unsigned short u16x4  __attribute__((ext_vector_type(4)));
typedef unsigned short u16x8  __attribute__((ext_vector_type(8)));
typedef float          f32x4  __attribute__((ext_vector_type(4)));

typedef const __attribute__((address_space(1))) void gvoid_t;
typedef __attribute__((address_space(3))) void       svoid_t;

static __device__ __forceinline__ u16 f2bf(float f) {
  union { float f; uint32_t u; } v; v.f = f;
  uint32_t u = v.u;
  return (u16)((u + 0x7FFFu + ((u >> 16) & 1u)) >> 16);  // RNE
}
static __device__ __forceinline__ float bf2f(u16 h) {
  union { uint32_t u; float f; } v; v.u = ((uint32_t)h) << 16;
  return v.f;
}
// RNE f32->bf16 via intrinsic (compiler emits packed cvt where possible)
static __device__ __forceinline__ u16 f2bf_hw(float f) {
  union { __hip_bfloat16 b; u16 u; } v;
  v.b = __float2bfloat16(f);
  return v.u;
}

// ------- prep: weights bf16 + conv_w transpose + CLS-row copy -------
__global__ void prep_small(const float4* __restrict__ x4, float4* __restrict__ out4,
                           const float* __restrict__ W1, const float* __restrict__ W2,
                           const float* __restrict__ cw, u16* __restrict__ w1b,
                           u16* __restrict__ w2b, float* __restrict__ cwT) {
  int i = blockIdx.x * blockDim.x + threadIdx.x;
  if (i < CADIM * CDIM) { w1b[i] = f2bf(W1[i]); w2b[i] = f2bf(W2[i]); }
  if (i < CADIM * 27) {
    int a = i / 27; int tap = i - a * 27;
    cwT[tap * CADIM + a] = cw[i];        // [27][384] channel-contiguous
  }
  if (i < BTOT * 192) {                  // CLS rows: 256 frames x 192 float4
    int f = i / 192, v = i - f * 192;
    size_t off = (size_t)f * (LX * CDIM / 4) + v;
    out4[off] = x4[off];
  }
}

// ======================================================================
// GEMM LDS layout (per buffer, per operand): super-row R (128 B) holds
// rows {2R, 2R+1} (32 bf16 each). Unswizzled slot u (0..7): u<4 -> row 2R
// chunk u; u>=4 -> row 2R+1 chunk u-4. Physical slot = u ^ (R&7).
// ds_read_b128 frag reads land 2 lanes/bank (free); gload_lds dst linear.
//
// fc1: BM=128 x BN=384 (x staged once), 768 thr / 12 waves; waves 0-3
// reg-stage A from fp32 x, waves 4-11 stage B via gload_lds (R6/R8).
// fc2: R1-exact 128x128 + T1 XCD-bijective swizzle (R8 win, fc2 ~91us).
// dwconv (THIS ROUND): f32 LDS tile + XOR-swizzled float4 slots + 2x2
// register blocking -- converts once at staging (74 vs 864 cvt/thread),
// halves LDS reads vs R7 (96 vs 216 b128/thread).
// ======================================================================

// ---------------- fc1: h1[m, a] = x[m,:] . W1[a,:] + b1[a] ----------------
__global__ __launch_bounds__(768, 2) void fc1_gemm(
    const float* __restrict__ X,  // x fp32 [BTOT][LX][CDIM]
    const u16* __restrict__ Bw,   // w1b [384][768] bf16 (N x K row-major)
    const float* __restrict__ bias,
    u16* __restrict__ Hout)       // [50176][384] bf16
{
  __shared__ __align__(16) u16 As[2 * 128 * 32];   // 16 KB
  __shared__ __align__(16) u16 Bs[2 * 384 * 32];   // 48 KB
  const int tid  = threadIdx.x;
  const int lane = tid & 63;
  const int wave = tid >> 6;           // 0..11
  const int m0 = blockIdx.x * 128;
  const int lm = lane & 15;
  const int lk = lane >> 4;
  const int wr = wave / 6;             // 0..1  (M half)
  const int wc = wave - wr * 6;        // 0..5  (N sixth)
  const int wm = wr * 64;
  const int wn = wc * 64;
  const bool is_a = (wave < 4);

  // ---- A reg-staging (waves 0-3): thread t: rows g+32s (g=t>>3), float4 q
  const int g = tid >> 3;              // 0..31 when is_a
  const int q = tid & 7;
  size_t arow[4];
  int awst[4];
  if (is_a) {
#pragma unroll
    for (int s = 0; s < 4; ++s) {
      int row = g + 32 * s;
      int tok = m0 + row;
      int bt = tok / LM1;
      int l  = tok - bt * LM1;
      arow[s] = (size_t)(bt * LX + 1 + l) * CDIM + q * 4;   // fp32, skip CLS
      int R    = row >> 1;
      int uu   = (row & 1) * 4 + (q >> 1);
      int slot = uu ^ (R & 7);
      awst[s]  = R * 64 + slot * 8 + (q & 1) * 4;           // u16 elems
    }
  }

  // ---- B staging (waves 4-11): 8 waves x 3 instrs cover 384 rows.
  const int wb  = wave - 4;            // 0..7 when !is_a
  const int u   = (lane & 7) ^ (lane >> 3);
  const int rr  = 2 * (lane >> 3) + (u >> 2);
  const int cko = (u & 3) * 8;
  size_t boff[3];
  int ldst[3];
  if (!is_a) {
#pragma unroll
    for (int s = 0; s < 3; ++s) {
      int row = wb * 48 + s * 16 + rr;
      boff[s] = (size_t)row * CDIM + cko;
      ldst[s] = (wb * 24 + s * 8) * 64;                     // u16 elems
    }
  }

  // fragment read addressing (swizzled)
  const int lmh   = lm >> 1;
  const int slotp = (((lm & 1) << 2) | lk) ^ lmh;
  const int abase = ((wm >> 1) + lmh) * 64 + slotp * 8;
  const int bbase = ((wn >> 1) + lmh) * 64 + slotp * 8;

  f32x4 acc[4][4];
#pragma unroll
  for (int i = 0; i < 4; i++)
#pragma unroll
    for (int j = 0; j < 4; j++) acc[i][j] = (f32x4)0.0f;

  float4 areg[4];

  // ---- prologue: tile 0 ----
  if (is_a) {
#pragma unroll
    for (int s = 0; s < 4; ++s) areg[s] = *(const float4*)(X + arow[s]);
#pragma unroll
    for (int s = 0; s < 4; ++s) {
      u16x4 o;
      o[0] = f2bf_hw(areg[s].x); o[1] = f2bf_hw(areg[s].y);
      o[2] = f2bf_hw(areg[s].z); o[3] = f2bf_hw(areg[s].w);
      *(u16x4*)&As[awst[s]] = o;
    }
  } else {
#pragma unroll
    for (int s = 0; s < 3; ++s)
      __builtin_amdgcn_global_load_lds((gvoid_t*)(Bw + boff[s]),
          (svoid_t*)(Bs + ldst[s]), 16, 0, 0);
  }
  __syncthreads();

  // ---- K = 768 -> 24 steps of 32, 2-phase double-buffered ----
  int cur = 0;
  for (int kt = 0; kt < 23; ++kt) {
    const int k1 = (kt + 1) * 32;
    const int nb = cur ^ 1;
    if (is_a) {
#pragma unroll
      for (int s = 0; s < 4; ++s) areg[s] = *(const float4*)(X + arow[s] + k1);
    } else {
#pragma unroll
      for (int s = 0; s < 3; ++s)
        __builtin_amdgcn_global_load_lds((gvoid_t*)(Bw + boff[s] + k1),
            (svoid_t*)(Bs + nb * 12288 + ldst[s]), 16, 0, 0);
    }
    {
      const u16* Ab = As + cur * 4096;
      const u16* Bb = Bs + cur * 12288;
      bf16x8 af[4], bfr[4];
#pragma unroll
      for (int i = 0; i < 4; i++) af[i] = *(const bf16x8*)&Ab[abase + i * 512];
#pragma unroll
      for (int j = 0; j < 4; j++) bfr[j] = *(const bf16x8*)&Bb[bbase + j * 512];
#pragma unroll
      for (int i = 0; i < 4; i++)
#pragma unroll
        for (int j = 0; j < 4; j++)
          acc[i][j] = __builtin_amdgcn_mfma_f32_16x16x32_bf16(af[i], bfr[j], acc[i][j], 0, 0, 0);
    }
    if (is_a) {
#pragma unroll
      for (int s = 0; s < 4; ++s) {
        u16x4 o;
        o[0] = f2bf_hw(areg[s].x); o[1] = f2bf_hw(areg[s].y);
        o[2] = f2bf_hw(areg[s].z); o[3] = f2bf_hw(areg[s].w);
        *(u16x4*)&As[nb * 4096 + awst[s]] = o;
      }
    }
    __syncthreads();
    cur ^= 1;
  }
  {
    const u16* Ab = As + cur * 4096;
    const u16* Bb = Bs + cur * 12288;
    bf16x8 af[4], bfr[4];
#pragma unroll
    for (int i = 0; i < 4; i++) af[i] = *(const bf16x8*)&Ab[abase + i * 512];
#pragma unroll
    for (int j = 0; j < 4; j++) bfr[j] = *(const bf16x8*)&Bb[bbase + j * 512];
#pragma unroll
    for (int i = 0; i < 4; i++)
#pragma unroll
      for (int j = 0; j < 4; j++)
        acc[i][j] = __builtin_amdgcn_mfma_f32_16x16x32_bf16(af[i], bfr[j], acc[i][j], 0, 0, 0);
  }

#pragma unroll
  for (int i = 0; i < 4; i++) {
    int rbase = m0 + wm + i * 16 + lk * 4;
#pragma unroll
    for (int j = 0; j < 4; j++) {
      int col = wn + j * 16 + lm;
      float bv = bias[col];
#pragma unroll
      for (int r = 0; r < 4; r++)
        Hout[(rbase + r) * CADIM + col] = f2bf(acc[i][j][r] + bv);
    }
  }
}

// ---------------- depthwise 3x3x3 conv: f32-LDS tile, 2x2 reg-blocked ----
// Block = (frame f, 32-ch chunk cc). Stage 3x196x32 values as f32
// (bf16->f32 ONCE at staging) into XOR-swizzled float4 slots:
//   slot(pos, c) = pos*8 + (c ^ (pos&7)),  c = float4 index 0..7
// (same involution on write and read -- conflict-free b128, 16B-aligned,
// no pad -> LDS 75,264 B -> 2 blocks/CU).
// Compute: thread = (patch 0..48, cg 0..3), 2x2 spatial outputs x 8 ch;
// each loaded float8 reused for up to 4 outputs (96 b128 reads/thread).
__global__ __launch_bounds__(256) void dwconv(
    const u16* __restrict__ h1, const float* __restrict__ cwT,
    const float* __restrict__ cb, u16* __restrict__ h2)
{
  __shared__ __align__(16) float lin[3 * 196 * 32];   // 75,264 B
  const int tid = threadIdx.x;
  const int f   = blockIdx.x;          // frame 0..255
  const int cc  = blockIdx.y;          // 0..11, channels cc*32..+31
  const int tv  = f & 7;               // t within video

  // ---- stage: 2352 bf16x8 chunks -> f32, swizzled float4 pairs ----
  for (int i = tid; i < 3 * 196 * 4; i += 256) {
    int fd  = i / 784;                 // 0..2 (= dt+1)
    int rem = i - fd * 784;            // pos*4 + c8
    int pos = rem >> 2;
    int c8  = rem & 3;
    int tt  = tv + fd - 1;
    float vf[8];
#pragma unroll
    for (int c = 0; c < 8; ++c) vf[c] = 0.0f;
    if (tt >= 0 && tt < TFR) {
      const u16x8 v = *(const u16x8*)(h1 + ((size_t)(f + fd - 1) * LM1 + pos) * CADIM
                                         + cc * 32 + c8 * 8);
#pragma unroll
      for (int c = 0; c < 8; ++c) vf[c] = bf2f((u16)v[c]);
    }
    const int p7 = pos & 7;
    const int s0 = (fd * 196 + pos) * 8;       // float4 slots base of this pos
    f32x4 a, b;
    a[0] = vf[0]; a[1] = vf[1]; a[2] = vf[2]; a[3] = vf[3];
    b[0] = vf[4]; b[1] = vf[5]; b[2] = vf[6]; b[3] = vf[7];
    *(f32x4*)&lin[(s0 + ((c8 * 2) ^ p7)) * 4]     = a;
    *(f32x4*)&lin[(s0 + ((c8 * 2 + 1) ^ p7)) * 4] = b;
  }
  __syncthreads();

  const int patch = tid >> 2;          // 0..63, valid < 49
  const int cg    = tid & 3;           // 8-ch group
  const int cbase = cc * 32 + cg * 8;
  if (patch < 49) {
    const int hp = patch / 7, wp = patch - hp * 7;
    const int h0 = hp * 2, w0 = wp * 2;

    float acc[2][2][8];
#pragma unroll
    for (int c = 0; c < 8; ++c) {
      float bv = cb[cbase + c];
      acc[0][0][c] = bv; acc[0][1][c] = bv; acc[1][0][c] = bv; acc[1][1][c] = bv;
    }

    for (int dt = 0; dt < 3; ++dt) {
      // plane weights (9 taps x 8 ch) hoisted; reused by all 4 outputs
      float wreg[9][8];
#pragma unroll
      for (int j = 0; j < 9; ++j) {
        const float* wp8 = cwT + (dt * 9 + j) * CADIM + cbase;
#pragma unroll
        for (int c = 0; c < 8; ++c) wreg[j][c] = wp8[c];
      }
#pragma unroll
      for (int ih = 0; ih < 4; ++ih) {
        int hh = h0 - 1 + ih;
        if (hh < 0 || hh >= 14) continue;
#pragma unroll
        for (int iw = 0; iw < 4; ++iw) {
          int ww = w0 - 1 + iw;
          if (ww < 0 || ww >= 14) continue;
          const int pos = hh * 14 + ww;
          const int p7  = pos & 7;
          const int s0  = (dt * 196 + pos) * 8;
          const f32x4 va = *(const f32x4*)&lin[(s0 + ((cg * 2) ^ p7)) * 4];
          const f32x4 vb = *(const f32x4*)&lin[(s0 + ((cg * 2 + 1) ^ p7)) * 4];
          float vf[8];
          vf[0] = va[0]; vf[1] = va[1]; vf[2] = va[2]; vf[3] = va[3];
          vf[4] = vb[0]; vf[5] = vb[1]; vf[6] = vb[2]; vf[7] = vb[3];
#pragma unroll
          for (int oh = 0; oh < 2; ++oh) {
            if (ih - 1 - oh < -1 || ih - 1 - oh > 1) continue;   // compile-time
#pragma unroll
            for (int ow = 0; ow < 2; ++ow) {
              if (iw - 1 - ow < -1 || iw - 1 - ow > 1) continue; // compile-time
              const int j = (ih - oh) * 3 + (iw - ow);           // (dh+1)*3+(dw+1)
#pragma unroll
              for (int c = 0; c < 8; ++c)
                acc[oh][ow][c] += vf[c] * wreg[j][c];
            }
          }
        }
      }
    }

    const size_t obase = (size_t)f * LM1 * CADIM + cbase;
#pragma unroll
    for (int oh = 0; oh < 2; ++oh)
#pragma unroll
      for (int ow = 0; ow < 2; ++ow) {
        u16x8 o;
#pragma unroll
        for (int c = 0; c < 8; ++c) o[c] = f2bf(acc[oh][ow][c]);
        *(u16x8*)(h2 + obase + ((size_t)(h0 + oh) * 14 + w0 + ow) * CADIM) = o;
      }
  }
}

// ---------------- fc2 + residual: out = x + h2 . W2^T + b2 ----------------
// R1-exact structure + T1 XCD-aware bijective swizzle (R8 win).
__global__ __launch_bounds__(256) void fc2_gemm(
    const u16* __restrict__ A,    // h2 [50176][384] bf16
    const u16* __restrict__ Bw,   // w2b [768][384] bf16 (N x K row-major)
    const float* __restrict__ bias,
    const float* __restrict__ x,
    float* __restrict__ out)
{
  __shared__ __align__(16) u16 As[2 * 128 * 32];
  __shared__ __align__(16) u16 Bs[2 * 128 * 32];
  const int tid  = threadIdx.x;
  const int lane = tid & 63;
  const int wave = tid >> 6;

  // T1 XCD swizzle: 2352 = 8*294 exactly; logical order A-stripe-major.
  const int orig = blockIdx.x;          // 0..2351
  const int lgc  = (orig & 7) * 294 + (orig >> 3);
  const int lmt  = lgc / 6;             // A-stripe (m-tile) 0..391
  const int lnt  = lgc - lmt * 6;       // n-tile 0..5
  const int m0 = lmt * 128;
  const int n0 = lnt * 128;

  const int lm = lane & 15;
  const int lk = lane >> 4;
  const int wm = (wave & 1) * 64;
  const int wn = (wave >> 1) * 64;

  const int u   = (lane & 7) ^ (lane >> 3);
  const int rr  = 2 * (lane >> 3) + (u >> 2);
  const int cko = (u & 3) * 8;
  size_t aoff[2], boff[2];
  int ldst[2];
#pragma unroll
  for (int s = 0; s < 2; ++s) {
    int row = wave * 32 + s * 16 + rr;
    aoff[s] = (size_t)(m0 + row) * CADIM + cko;
    boff[s] = (size_t)(n0 + row) * CADIM + cko;
    ldst[s] = (wave * 16 + s * 8) * 64;
  }

  const int lmh   = lm >> 1;
  const int slotp = (((lm & 1) << 2) | lk) ^ lmh;
  const int abase = ((wm >> 1) + lmh) * 64 + slotp * 8;
  const int bbase = ((wn >> 1) + lmh) * 64 + slotp * 8;

  f32x4 acc[4][4];
#pragma unroll
  for (int i = 0; i < 4; i++)
#pragma unroll
    for (int j = 0; j < 4; j++) acc[i][j] = (f32x4)0.0f;

  // K = 384 -> 12 steps of 32, double-buffered (R1-exact)
#pragma unroll
  for (int s = 0; s < 2; ++s) {
    __builtin_amdgcn_global_load_lds((gvoid_t*)(A + aoff[s]),
        (svoid_t*)(As + ldst[s]), 16, 0, 0);
    __builtin_amdgcn_global_load_lds((gvoid_t*)(Bw + boff[s]),
        (svoid_t*)(Bs + ldst[s]), 16, 0, 0);
  }
  __syncthreads();
  int cur = 0;
  for (int kt = 0; kt < 11; ++kt) {
    const int k1 = (kt + 1) * 32;
    const int nb = cur ^ 1;
#pragma unroll
    for (int s = 0; s < 2; ++s) {
      __builtin_amdgcn_global_load_lds((gvoid_t*)(A + aoff[s] + k1),
          (svoid_t*)(As + nb * 4096 + ldst[s]), 16, 0, 0);
      __builtin_amdgcn_global_load_lds((gvoid_t*)(Bw + boff[s] + k1),
          (svoid_t*)(Bs + nb * 4096 + ldst[s]), 16, 0, 0);
    }
    {
      const u16* Ab = As + cur * 4096;
      const u16* Bb = Bs + cur * 4096;
      bf16x8 af[4], bfr[4];
#pragma unroll
      for (int i = 0; i < 4; i++) af[i] = *(const bf16x8*)&Ab[abase + i * 512];
#pragma unroll
      for (int j = 0; j < 4; j++) bfr[j] = *(const bf16x8*)&Bb[bbase + j * 512];
#pragma unroll
      for (int i = 0; i < 4; i++)
#pragma unroll
        for (int j = 0; j < 4; j++)
          acc[i][j] = __builtin_amdgcn_mfma_f32_16x16x32_bf16(af[i], bfr[j], acc[i][j], 0, 0, 0);
    }
    __syncthreads();
    cur ^= 1;
  }
  {
    const u16* Ab = As + cur * 4096;
    const u16* Bb = Bs + cur * 4096;
    bf16x8 af[4], bfr[4];
#pragma unroll
    for (int i = 0; i < 4; i++) af[i] = *(const bf16x8*)&Ab[abase + i * 512];
#pragma unroll
    for (int j = 0; j < 4; j++) bfr[j] = *(const bf16x8*)&Bb[bbase + j * 512];
#pragma unroll
    for (int i = 0; i < 4; i++)
#pragma unroll
      for (int j = 0; j < 4; j++)
        acc[i][j] = __builtin_amdgcn_mfma_f32_16x16x32_bf16(af[i], bfr[j], acc[i][j], 0, 0, 0);
  }

  // epilogue (R1-exact): residual add + bias, fp32 out.
  float bv[4];
#pragma unroll
  for (int j = 0; j < 4; j++) bv[j] = bias[n0 + wn + j * 16 + lm];
#pragma unroll
  for (int i = 0; i < 4; i++) {
    int rbase = m0 + wm + i * 16 + lk * 4;
    size_t orow[4];
#pragma unroll
    for (int r = 0; r < 4; r++) {
      int tok = rbase + r;
      int bt = tok / LM1;
      int l  = tok - bt * LM1;
      orow[r] = (size_t)(bt * LX + 1 + l) * CDIM + (n0 + wn + lm);
    }
    float xv[4][4];
#pragma unroll
    for (int r = 0; r < 4; r++)
#pragma unroll
      for (int j = 0; j < 4; j++)
        xv[r][j] = x[orow[r] + j * 16];
#pragma unroll
    for (int r = 0; r < 4; r++)
#pragma unroll
      for (int j = 0; j < 4; j++)
        out[orow[r] + j * 16] = xv[r][j] + acc[i][j][r] + bv[j];
  }
}

// ---------------- launch ----------------
extern "C" void kernel_launch(void* const* d_in, const int* in_sizes, int n_in,
                              void* d_out, int out_size, void* d_ws, size_t ws_size,
                              hipStream_t stream) {
  const float* x  = (const float*)d_in[0];
  const float* W1 = (const float*)d_in[1];
  const float* b1 = (const float*)d_in[2];
  const float* cw = (const float*)d_in[3];
  const float* cb = (const float*)d_in[4];
  const float* W2 = (const float*)d_in[5];
  const float* b2 = (const float*)d_in[6];
  float* out = (float*)d_out;

  // workspace: 78.3 MB total
  char* ws = (char*)d_ws;
  u16*   w1b = (u16*)(ws + 0);              //    589,824 B
  u16*   w2b = (u16*)(ws + 589824);         //    589,824 B
  float* cwT = (float*)(ws + 1179648);      //     41,472 B
  u16*   h1  = (u16*)(ws + 1245184);        // 38,535,168 B
  u16*   h2  = (u16*)(ws + 39780352);       // 38,535,168 B  (end 78,315,520)

  prep_small<<<1152, 256, 0, stream>>>((const float4*)x, (float4*)out,
                                       W1, W2, cw, w1b, w2b, cwT);
  fc1_gemm<<<MTOT / 128, 768, 0, stream>>>(x, w1b, b1, h1);
  dwconv  <<<dim3(BTOT, 12), 256, 0, stream>>>(h1, cwT, cb, h2);
  fc2_gemm<<<2352, 256, 0, stream>>>(h2, w2b, b2, x, out);
}

// Round 10
// 433.249 us; speedup vs baseline: 1.0165x; 1.0165x over previous
//
#include <hip/hip_runtime.h>
#include <hip/hip_bf16.h>
#include <stdint.h>

// ---- problem constants (fixed shapes) ----
#define BTOT   256      // B*T frames
#define LX     197      // tokens incl CLS
#define CDIM   768
#define CADIM  384
#define TFR    8
#define LM1    196      // L-1
#define MTOT   50176    // BTOT*LM1

typedef unsigned short u16;
typedef short          bf16x8 __attribute__((ext_vector_type(8)));
typedef unsigned short u16x4  __attribute__((ext_vector_type(4)));
typedef unsigned short u16x8  __attribute__((ext_vector_type(8)));
typedef float          f32x4  __attribute__((ext_vector_type(4)));

typedef const __attribute__((address_space(1))) void gvoid_t;
typedef __attribute__((address_space(3))) void       svoid_t;

static __device__ __forceinline__ u16 f2bf(float f) {
  union { float f; uint32_t u; } v; v.f = f;
  uint32_t u = v.u;
  return (u16)((u + 0x7FFFu + ((u >> 16) & 1u)) >> 16);  // RNE
}
static __device__ __forceinline__ float bf2f(u16 h) {
  union { uint32_t u; float f; } v; v.u = ((uint32_t)h) << 16;
  return v.f;
}
// RNE f32->bf16 via intrinsic (compiler emits packed cvt where possible)
static __device__ __forceinline__ u16 f2bf_hw(float f) {
  union { __hip_bfloat16 b; u16 u; } v;
  v.b = __float2bfloat16(f);
  return v.u;
}

// ------- prep: weights bf16 + conv_w transpose + CLS-row copy -------
__global__ void prep_small(const float4* __restrict__ x4, float4* __restrict__ out4,
                           const float* __restrict__ W1, const float* __restrict__ W2,
                           const float* __restrict__ cw, u16* __restrict__ w1b,
                           u16* __restrict__ w2b, float* __restrict__ cwT) {
  int i = blockIdx.x * blockDim.x + threadIdx.x;
  if (i < CADIM * CDIM) { w1b[i] = f2bf(W1[i]); w2b[i] = f2bf(W2[i]); }
  if (i < CADIM * 27) {
    int a = i / 27; int tap = i - a * 27;
    cwT[tap * CADIM + a] = cw[i];        // [27][384] channel-contiguous
  }
  if (i < BTOT * 192) {                  // CLS rows: 256 frames x 192 float4
    int f = i / 192, v = i - f * 192;
    size_t off = (size_t)f * (LX * CDIM / 4) + v;
    out4[off] = x4[off];
  }
}

// ======================================================================
// GEMM LDS layout (per buffer, per operand): super-row R (128 B) holds
// rows {2R, 2R+1} (32 bf16 each). Unswizzled slot u (0..7): u<4 -> row 2R
// chunk u; u>=4 -> row 2R+1 chunk u-4. Physical slot = u ^ (R&7).
// ds_read_b128 frag reads land 2 lanes/bank (free); gload_lds dst linear.
//
// fc1: BM=128 x BN=384 (x staged once), 768 thr / 12 waves.
// THIS ROUND: staging rebalanced -- A (load+cvt+write chain, the
// barrier-critical path) spread over waves 0-7 (2 float4/thread, was 4
// over waves 0-3); B issue-only gload_lds moved to waves 8-11
// (6/thread). Halves the heaviest wave's chain at each barrier.
// fc2: R1-exact 128x128 + T1 XCD-bijective swizzle (R8 win, ~91us).
// dwconv: R7/R8 bf16-LDS version (R9's f32 variant regressed +6us).
// ======================================================================

// ---------------- fc1: h1[m, a] = x[m,:] . W1[a,:] + b1[a] ----------------
__global__ __launch_bounds__(768, 2) void fc1_gemm(
    const float* __restrict__ X,  // x fp32 [BTOT][LX][CDIM]
    const u16* __restrict__ Bw,   // w1b [384][768] bf16 (N x K row-major)
    const float* __restrict__ bias,
    u16* __restrict__ Hout)       // [50176][384] bf16
{
  __shared__ __align__(16) u16 As[2 * 128 * 32];   // 16 KB
  __shared__ __align__(16) u16 Bs[2 * 384 * 32];   // 48 KB
  const int tid  = threadIdx.x;
  const int lane = tid & 63;
  const int wave = tid >> 6;           // 0..11
  const int m0 = blockIdx.x * 128;
  const int lm = lane & 15;
  const int lk = lane >> 4;
  const int wr = wave / 6;             // 0..1  (M half)
  const int wc = wave - wr * 6;        // 0..5  (N sixth)
  const int wm = wr * 64;
  const int wn = wc * 64;
  const bool is_a = (wave < 8);        // A-staging: waves 0-7 (512 thr)

  // ---- A reg-staging (waves 0-7): thread t: rows (t>>3)+64s, float4 q
  const int g = tid >> 3;              // 0..63 when is_a
  const int q = tid & 7;
  size_t arow[2];
  int awst[2];
  if (is_a) {
#pragma unroll
    for (int s = 0; s < 2; ++s) {
      int row = g + 64 * s;
      int tok = m0 + row;
      int bt = tok / LM1;
      int l  = tok - bt * LM1;
      arow[s] = (size_t)(bt * LX + 1 + l) * CDIM + q * 4;   // fp32, skip CLS
      int R    = row >> 1;
      int uu   = (row & 1) * 4 + (q >> 1);
      int slot = uu ^ (R & 7);
      awst[s]  = R * 64 + slot * 8 + (q & 1) * 4;           // u16 elems
    }
  }

  // ---- B staging (waves 8-11): 4 waves x 6 instrs cover 384 rows.
  const int wb  = wave - 8;            // 0..3 when !is_a
  const int u   = (lane & 7) ^ (lane >> 3);
  const int rr  = 2 * (lane >> 3) + (u >> 2);
  const int cko = (u & 3) * 8;
  size_t boff[6];
  int ldst[6];
  if (!is_a) {
#pragma unroll
    for (int s = 0; s < 6; ++s) {
      int row = wb * 96 + s * 16 + rr;
      boff[s] = (size_t)row * CDIM + cko;
      ldst[s] = (wb * 48 + s * 8) * 64;                     // u16 elems
    }
  }

  // fragment read addressing (swizzled)
  const int lmh   = lm >> 1;
  const int slotp = (((lm & 1) << 2) | lk) ^ lmh;
  const int abase = ((wm >> 1) + lmh) * 64 + slotp * 8;
  const int bbase = ((wn >> 1) + lmh) * 64 + slotp * 8;

  f32x4 acc[4][4];
#pragma unroll
  for (int i = 0; i < 4; i++)
#pragma unroll
    for (int j = 0; j < 4; j++) acc[i][j] = (f32x4)0.0f;

  float4 areg[2];

  // ---- prologue: tile 0 ----
  if (is_a) {
#pragma unroll
    for (int s = 0; s < 2; ++s) areg[s] = *(const float4*)(X + arow[s]);
#pragma unroll
    for (int s = 0; s < 2; ++s) {
      u16x4 o;
      o[0] = f2bf_hw(areg[s].x); o[1] = f2bf_hw(areg[s].y);
      o[2] = f2bf_hw(areg[s].z); o[3] = f2bf_hw(areg[s].w);
      *(u16x4*)&As[awst[s]] = o;
    }
  } else {
#pragma unroll
    for (int s = 0; s < 6; ++s)
      __builtin_amdgcn_global_load_lds((gvoid_t*)(Bw + boff[s]),
          (svoid_t*)(Bs + ldst[s]), 16, 0, 0);
  }
  __syncthreads();

  // ---- K = 768 -> 24 steps of 32, 2-phase double-buffered ----
  int cur = 0;
  for (int kt = 0; kt < 23; ++kt) {
    const int k1 = (kt + 1) * 32;
    const int nb = cur ^ 1;
    if (is_a) {
#pragma unroll
      for (int s = 0; s < 2; ++s) areg[s] = *(const float4*)(X + arow[s] + k1);
    } else {
#pragma unroll
      for (int s = 0; s < 6; ++s)
        __builtin_amdgcn_global_load_lds((gvoid_t*)(Bw + boff[s] + k1),
            (svoid_t*)(Bs + nb * 12288 + ldst[s]), 16, 0, 0);
    }
    {
      const u16* Ab = As + cur * 4096;
      const u16* Bb = Bs + cur * 12288;
      bf16x8 af[4], bfr[4];
#pragma unroll
      for (int i = 0; i < 4; i++) af[i] = *(const bf16x8*)&Ab[abase + i * 512];
#pragma unroll
      for (int j = 0; j < 4; j++) bfr[j] = *(const bf16x8*)&Bb[bbase + j * 512];
#pragma unroll
      for (int i = 0; i < 4; i++)
#pragma unroll
        for (int j = 0; j < 4; j++)
          acc[i][j] = __builtin_amdgcn_mfma_f32_16x16x32_bf16(af[i], bfr[j], acc[i][j], 0, 0, 0);
    }
    if (is_a) {
#pragma unroll
      for (int s = 0; s < 2; ++s) {
        u16x4 o;
        o[0] = f2bf_hw(areg[s].x); o[1] = f2bf_hw(areg[s].y);
        o[2] = f2bf_hw(areg[s].z); o[3] = f2bf_hw(areg[s].w);
        *(u16x4*)&As[nb * 4096 + awst[s]] = o;
      }
    }
    __syncthreads();
    cur ^= 1;
  }
  {
    const u16* Ab = As + cur * 4096;
    const u16* Bb = Bs + cur * 12288;
    bf16x8 af[4], bfr[4];
#pragma unroll
    for (int i = 0; i < 4; i++) af[i] = *(const bf16x8*)&Ab[abase + i * 512];
#pragma unroll
    for (int j = 0; j < 4; j++) bfr[j] = *(const bf16x8*)&Bb[bbase + j * 512];
#pragma unroll
    for (int i = 0; i < 4; i++)
#pragma unroll
      for (int j = 0; j < 4; j++)
        acc[i][j] = __builtin_amdgcn_mfma_f32_16x16x32_bf16(af[i], bfr[j], acc[i][j], 0, 0, 0);
  }

#pragma unroll
  for (int i = 0; i < 4; i++) {
    int rbase = m0 + wm + i * 16 + lk * 4;
#pragma unroll
    for (int j = 0; j < 4; j++) {
      int col = wn + j * 16 + lm;
      float bv = bias[col];
#pragma unroll
      for (int r = 0; r < 4; r++)
        Hout[(rbase + r) * CADIM + col] = f2bf(acc[i][j][r] + bv);
    }
  }
}

// ---------------- depthwise 3x3x3 conv: LDS-tiled (R7/R8 version) ----------
__global__ __launch_bounds__(256) void dwconv(
    const u16* __restrict__ h1, const float* __restrict__ cwT,
    const float* __restrict__ cb, u16* __restrict__ h2)
{
  __shared__ __align__(16) u16 lin[3 * 196 * 32];   // 37,632 B
  const int tid = threadIdx.x;
  const int f   = blockIdx.x;          // frame 0..255
  const int cc  = blockIdx.y;          // 0..11, channels cc*32..+31
  const int tv  = f & 7;               // t within video

  // ---- stage: 2352 16B-chunks; zero-fill temporally-invalid frames ----
  for (int i = tid; i < 3 * 196 * 4; i += 256) {
    int fd  = i / 784;                 // 0..2 (= dt+1)
    int rem = i - fd * 784;            // pos*4 + c8
    int pos = rem >> 2;
    int c8  = rem & 3;
    int tt  = tv + fd - 1;
    u16x8 v = (u16x8)0;
    if (tt >= 0 && tt < TFR) {
      const u16* src = h1 + ((size_t)(f + fd - 1) * LM1 + pos) * CADIM
                          + cc * 32 + c8 * 8;
      v = *(const u16x8*)src;
    }
    *(u16x8*)&lin[(fd * 196 + pos) * 32 + c8 * 8] = v;
  }
  __syncthreads();

  const int cg    = tid & 3;           // 8-ch group within the 32
  const int pidx  = tid >> 2;          // 0..63
  const int cbase = cc * 32 + cg * 8;

  float bv[8];
#pragma unroll
  for (int c = 0; c < 8; ++c) bv[c] = cb[cbase + c];

  float acc[4][8];
  int hk[4], wk[4];
#pragma unroll
  for (int k = 0; k < 4; ++k) {
    int p = pidx + 64 * k;
    hk[k] = p / 14;
    wk[k] = p - hk[k] * 14;
#pragma unroll
    for (int c = 0; c < 8; ++c) acc[k][c] = bv[c];
  }

  for (int dt = 0; dt < 3; ++dt) {
#pragma unroll
    for (int j = 0; j < 9; ++j) {
      const int dh = j / 3 - 1, dw = j % 3 - 1;
      float w8[8];
      const float* wp8 = cwT + (dt * 9 + j) * CADIM + cbase;
#pragma unroll
      for (int c = 0; c < 8; ++c) w8[c] = wp8[c];
#pragma unroll
      for (int k = 0; k < 4; ++k) {
        int p = pidx + 64 * k;
        if (p >= 196) continue;
        int hh = hk[k] + dh, ww = wk[k] + dw;
        if (hh < 0 || hh >= 14 || ww < 0 || ww >= 14) continue;
        const u16x8 v = *(const u16x8*)&lin[(dt * 196 + hh * 14 + ww) * 32 + cg * 8];
#pragma unroll
        for (int c = 0; c < 8; ++c)
          acc[k][c] += bf2f((u16)v[c]) * w8[c];
      }
    }
  }

#pragma unroll
  for (int k = 0; k < 4; ++k) {
    int p = pidx + 64 * k;
    if (p < 196) {
      u16x8 o;
#pragma unroll
      for (int c = 0; c < 8; ++c) o[c] = f2bf(acc[k][c]);
      *(u16x8*)(h2 + ((size_t)f * LM1 + p) * CADIM + cbase) = o;
    }
  }
}

// ---------------- fc2 + residual: out = x + h2 . W2^T + b2 ----------------
// R1-exact structure + T1 XCD-aware bijective swizzle (R8 win).
__global__ __launch_bounds__(256) void fc2_gemm(
    const u16* __restrict__ A,    // h2 [50176][384] bf16
    const u16* __restrict__ Bw,   // w2b [768][384] bf16 (N x K row-major)
    const float* __restrict__ bias,
    const float* __restrict__ x,
    float* __restrict__ out)
{
  __shared__ __align__(16) u16 As[2 * 128 * 32];
  __shared__ __align__(16) u16 Bs[2 * 128 * 32];
  const int tid  = threadIdx.x;
  const int lane = tid & 63;
  const int wave = tid >> 6;

  // T1 XCD swizzle: 2352 = 8*294 exactly; logical order A-stripe-major.
  const int orig = blockIdx.x;          // 0..2351
  const int lgc  = (orig & 7) * 294 + (orig >> 3);
  const int lmt  = lgc / 6;             // A-stripe (m-tile) 0..391
  const int lnt  = lgc - lmt * 6;       // n-tile 0..5
  const int m0 = lmt * 128;
  const int n0 = lnt * 128;

  const int lm = lane & 15;
  const int lk = lane >> 4;
  const int wm = (wave & 1) * 64;
  const int wn = (wave >> 1) * 64;

  const int u   = (lane & 7) ^ (lane >> 3);
  const int rr  = 2 * (lane >> 3) + (u >> 2);
  const int cko = (u & 3) * 8;
  size_t aoff[2], boff[2];
  int ldst[2];
#pragma unroll
  for (int s = 0; s < 2; ++s) {
    int row = wave * 32 + s * 16 + rr;
    aoff[s] = (size_t)(m0 + row) * CADIM + cko;
    boff[s] = (size_t)(n0 + row) * CADIM + cko;
    ldst[s] = (wave * 16 + s * 8) * 64;
  }

  const int lmh   = lm >> 1;
  const int slotp = (((lm & 1) << 2) | lk) ^ lmh;
  const int abase = ((wm >> 1) + lmh) * 64 + slotp * 8;
  const int bbase = ((wn >> 1) + lmh) * 64 + slotp * 8;

  f32x4 acc[4][4];
#pragma unroll
  for (int i = 0; i < 4; i++)
#pragma unroll
    for (int j = 0; j < 4; j++) acc[i][j] = (f32x4)0.0f;

  // K = 384 -> 12 steps of 32, double-buffered (R1-exact)
#pragma unroll
  for (int s = 0; s < 2; ++s) {
    __builtin_amdgcn_global_load_lds((gvoid_t*)(A + aoff[s]),
        (svoid_t*)(As + ldst[s]), 16, 0, 0);
    __builtin_amdgcn_global_load_lds((gvoid_t*)(Bw + boff[s]),
        (svoid_t*)(Bs + ldst[s]), 16, 0, 0);
  }
  __syncthreads();
  int cur = 0;
  for (int kt = 0; kt < 11; ++kt) {
    const int k1 = (kt + 1) * 32;
    const int nb = cur ^ 1;
#pragma unroll
    for (int s = 0; s < 2; ++s) {
      __builtin_amdgcn_global_load_lds((gvoid_t*)(A + aoff[s] + k1),
          (svoid_t*)(As + nb * 4096 + ldst[s]), 16, 0, 0);
      __builtin_amdgcn_global_load_lds((gvoid_t*)(Bw + boff[s] + k1),
          (svoid_t*)(Bs + nb * 4096 + ldst[s]), 16, 0, 0);
    }
    {
      const u16* Ab = As + cur * 4096;
      const u16* Bb = Bs + cur * 4096;
      bf16x8 af[4], bfr[4];
#pragma unroll
      for (int i = 0; i < 4; i++) af[i] = *(const bf16x8*)&Ab[abase + i * 512];
#pragma unroll
      for (int j = 0; j < 4; j++) bfr[j] = *(const bf16x8*)&Bb[bbase + j * 512];
#pragma unroll
      for (int i = 0; i < 4; i++)
#pragma unroll
        for (int j = 0; j < 4; j++)
          acc[i][j] = __builtin_amdgcn_mfma_f32_16x16x32_bf16(af[i], bfr[j], acc[i][j], 0, 0, 0);
    }
    __syncthreads();
    cur ^= 1;
  }
  {
    const u16* Ab = As + cur * 4096;
    const u16* Bb = Bs + cur * 4096;
    bf16x8 af[4], bfr[4];
#pragma unroll
    for (int i = 0; i < 4; i++) af[i] = *(const bf16x8*)&Ab[abase + i * 512];
#pragma unroll
    for (int j = 0; j < 4; j++) bfr[j] = *(const bf16x8*)&Bb[bbase + j * 512];
#pragma unroll
    for (int i = 0; i < 4; i++)
#pragma unroll
      for (int j = 0; j < 4; j++)
        acc[i][j] = __builtin_amdgcn_mfma_f32_16x16x32_bf16(af[i], bfr[j], acc[i][j], 0, 0, 0);
  }

  // epilogue (R1-exact): residual add + bias, fp32 out.
  float bv[4];
#pragma unroll
  for (int j = 0; j < 4; j++) bv[j] = bias[n0 + wn + j * 16 + lm];
#pragma unroll
  for (int i = 0; i < 4; i++) {
    int rbase = m0 + wm + i * 16 + lk * 4;
    size_t orow[4];
#pragma unroll
    for (int r = 0; r < 4; r++) {
      int tok = rbase + r;
      int bt = tok / LM1;
      int l  = tok - bt * LM1;
      orow[r] = (size_t)(bt * LX + 1 + l) * CDIM + (n0 + wn + lm);
    }
    float xv[4][4];
#pragma unroll
    for (int r = 0; r < 4; r++)
#pragma unroll
      for (int j = 0; j < 4; j++)
        xv[r][j] = x[orow[r] + j * 16];
#pragma unroll
    for (int r = 0; r < 4; r++)
#pragma unroll
      for (int j = 0; j < 4; j++)
        out[orow[r] + j * 16] = xv[r][j] + acc[i][j][r] + bv[j];
  }
}

// ---------------- launch ----------------
extern "C" void kernel_launch(void* const* d_in, const int* in_sizes, int n_in,
                              void* d_out, int out_size, void* d_ws, size_t ws_size,
                              hipStream_t stream) {
  const float* x  = (const float*)d_in[0];
  const float* W1 = (const float*)d_in[1];
  const float* b1 = (const float*)d_in[2];
  const float* cw = (const float*)d_in[3];
  const float* cb = (const float*)d_in[4];
  const float* W2 = (const float*)d_in[5];
  const float* b2 = (const float*)d_in[6];
  float* out = (float*)d_out;

  // workspace: 78.3 MB total
  char* ws = (char*)d_ws;
  u16*   w1b = (u16*)(ws + 0);              //    589,824 B
  u16*   w2b = (u16*)(ws + 589824);         //    589,824 B
  float* cwT = (float*)(ws + 1179648);      //     41,472 B
  u16*   h1  = (u16*)(ws + 1245184);        // 38,535,168 B
  u16*   h2  = (u16*)(ws + 39780352);       // 38,535,168 B  (end 78,315,520)

  prep_small<<<1152, 256, 0, stream>>>((const float4*)x, (float4*)out,
                                       W1, W2, cw, w1b, w2b, cwT);
  fc1_gemm<<<MTOT / 128, 768, 0, stream>>>(x, w1b, b1, h1);
  dwconv  <<<dim3(BTOT, 12), 256, 0, stream>>>(h1, cwT, cb, h2);
  fc2_gemm<<<2352, 256, 0, stream>>>(h2, w2b, b2, x, out);
}